// Round 9
// baseline (368.520 us; speedup 1.0000x reference)
//
#include <hip/hip_runtime.h>
#include <math.h>

#define SEQ 2048
#define DIM 1024
#define NH 16

typedef short s8v __attribute__((ext_vector_type(8)));
typedef short s4v __attribute__((ext_vector_type(4)));
typedef float f4v __attribute__((ext_vector_type(4)));

__device__ __forceinline__ unsigned short f2bf(float x) {   // RNE
    unsigned u = __float_as_uint(x);
    u += 0x7FFFu + ((u >> 16) & 1u);
    return (unsigned short)(u >> 16);
}
__device__ __forceinline__ unsigned cvt_pk_bf16(float lo, float hi) {
    unsigned r;
    asm("v_cvt_pk_bf16_f32 %0, %1, %2" : "=v"(r) : "v"(lo), "v"(hi));
    return r;
}

// ---------------- fused: q,k,v fp32->bf16  AND  4x W transpose->bf16 ----------------
__global__ __launch_bounds__(256)
void conv_all(const float* __restrict__ q, const float* __restrict__ k,
              const float* __restrict__ v,
              unsigned short* __restrict__ qb, unsigned short* __restrict__ kb,
              unsigned short* __restrict__ vb, int n4,
              const float* __restrict__ W0, const float* __restrict__ W1,
              const float* __restrict__ W2, const float* __restrict__ W3,
              unsigned short* __restrict__ T0, unsigned short* __restrict__ T1,
              unsigned short* __restrict__ T2, unsigned short* __restrict__ T3)
{
    __shared__ float T[64][65];
    const int t = threadIdx.x;
    if (blockIdx.y < 3) {
        const float* in = (blockIdx.y == 0) ? q : (blockIdx.y == 1) ? k : v;
        unsigned short* out = (blockIdx.y == 0) ? qb : (blockIdx.y == 1) ? kb : vb;
        int i = blockIdx.x * 256 + t;
        if (i >= n4) return;
        float4 x = ((const float4*)in)[i];
        ushort4 o;
        o.x = f2bf(x.x); o.y = f2bf(x.y); o.z = f2bf(x.z); o.w = f2bf(x.w);
        ((ushort4*)out)[i] = o;
        return;
    }
    int id = blockIdx.x;
    if (id >= 1024) return;
    const int wz = id >> 8, rem = id & 255;
    const int bxx = rem & 15, byy = rem >> 4;
    const float* W = (wz == 0) ? W0 : (wz == 1) ? W1 : (wz == 2) ? W2 : W3;
    unsigned short* WT = (wz == 0) ? T0 : (wz == 1) ? T1 : (wz == 2) ? T2 : T3;
    const int n0 = bxx * 64, k0 = byy * 64;
    #pragma unroll
    for (int i = 0; i < 4; i++) {
        int idx = t + i * 256;
        int r = idx >> 4, c4 = idx & 15;
        float4 vv = *(const float4*)&W[(size_t)(k0 + r) * DIM + n0 + c4 * 4];
        T[r][c4 * 4 + 0] = vv.x; T[r][c4 * 4 + 1] = vv.y;
        T[r][c4 * 4 + 2] = vv.z; T[r][c4 * 4 + 3] = vv.w;
    }
    __syncthreads();
    #pragma unroll
    for (int i = 0; i < 4; i++) {
        int idx = t + i * 256;
        int rn = idx >> 4, c4 = idx & 15;
        ushort4 o;
        o.x = f2bf(T[c4 * 4 + 0][rn]);
        o.y = f2bf(T[c4 * 4 + 1][rn]);
        o.z = f2bf(T[c4 * 4 + 2][rn]);
        o.w = f2bf(T[c4 * 4 + 3][rn]);
        *(ushort4*)&WT[(size_t)(n0 + rn) * DIM + k0 + c4 * 4] = o;
    }
}

// ---------------- GEMM core (m97 staging), shared by qkv+out projections ----------
// C = A[M,K]*BT[N,K]^T + bias. 128x128 tile, BK=64, global_load_lds staging.
// MODE 0: fp32 out [M,DIM] (direct stores);
// MODE 1: bf16 head-split [B,NH,SEQ,64]*scale  -- epilogue via LDS, b128 stores;
// MODE 2: bf16 head-split TRANSPOSED [B*NH][64][SEQ] -- epilogue via LDS, b128 stores.
template<int MODE>
__device__ __forceinline__
void gemm_core(const unsigned short* __restrict__ A,
               const unsigned short* __restrict__ BT,
               const float* __restrict__ bias, void* __restrict__ outp,
               float scale, int bx, int by)
{
    __shared__ __align__(16) unsigned short smem[17408];   // 34.8 KB (staging 32 KB / C-tile 34 KB)
    unsigned short* As = smem;
    unsigned short* Bs = smem + 128 * 64;
    const int t = threadIdx.x;
    const int lane = t & 63, w = t >> 6;
    const int l15 = lane & 15, quad = lane >> 4;
    const int bm = by * 128, bn = bx * 128;
    const int wm = (w & 1) * 64, wn = (w >> 1) * 64;
    const int lrow = lane >> 3, lcol = (lane & 7) * 8;

    f4v acc[4][4];
    #pragma unroll
    for (int mi = 0; mi < 4; mi++)
        #pragma unroll
        for (int ni = 0; ni < 4; ni++)
            acc[mi][ni] = (f4v){0.f, 0.f, 0.f, 0.f};

    for (int k0 = 0; k0 < DIM; k0 += 64) {
        __syncthreads();
        #pragma unroll
        for (int i = 0; i < 4; i++) {
            int ci = w + i * 4;
            int row = ci * 8 + lrow;
            __builtin_amdgcn_global_load_lds(
                (const __attribute__((address_space(1))) unsigned int*)
                    (A + (size_t)(bm + row) * DIM + k0 + lcol),
                (__attribute__((address_space(3))) unsigned int*)(As + ci * 8 * 64),
                16, 0, 0);
            __builtin_amdgcn_global_load_lds(
                (const __attribute__((address_space(1))) unsigned int*)
                    (BT + (size_t)(bn + row) * DIM + k0 + lcol),
                (__attribute__((address_space(3))) unsigned int*)(Bs + ci * 8 * 64),
                16, 0, 0);
        }
        __syncthreads();
        #pragma unroll
        for (int kc = 0; kc < 2; kc++) {
            const int ko = kc * 32 + quad * 8;
            s8v af[4], bf[4];
            #pragma unroll
            for (int mi = 0; mi < 4; mi++)
                af[mi] = *(const s8v*)&As[(wm + mi * 16 + l15) * 64 + ko];
            #pragma unroll
            for (int ni = 0; ni < 4; ni++)
                bf[ni] = *(const s8v*)&Bs[(wn + ni * 16 + l15) * 64 + ko];
            #pragma unroll
            for (int mi = 0; mi < 4; mi++)
                #pragma unroll
                for (int ni = 0; ni < 4; ni++)
                    acc[mi][ni] = __builtin_amdgcn_mfma_f32_16x16x32_bf16(
                        af[mi], bf[ni], acc[mi][ni], 0, 0, 0);
        }
    }

    if (MODE == 0) {
        #pragma unroll
        for (int mi = 0; mi < 4; mi++)
            #pragma unroll
            for (int ni = 0; ni < 4; ni++)
                #pragma unroll
                for (int r = 0; r < 4; r++) {
                    int m = bm + wm + mi * 16 + quad * 4 + r;
                    int n = bn + wn + ni * 16 + l15;
                    ((float*)outp)[(size_t)m * DIM + n] = acc[mi][ni][r] + bias[n];
                }
    } else {
        __syncthreads();              // all frag reads of As/Bs done -> reuse as Cs
        unsigned short* Cs = smem;    // [128][136] padded bf16 C tile
        if (MODE == 1) {
            #pragma unroll
            for (int mi = 0; mi < 4; mi++)
                #pragma unroll
                for (int ni = 0; ni < 4; ni++)
                    #pragma unroll
                    for (int r = 0; r < 4; r++) {
                        int ml = wm + mi * 16 + quad * 4 + r;
                        int nl = wn + ni * 16 + l15;
                        float val = (acc[mi][ni][r] + bias[bn + nl]) * scale;
                        Cs[ml * 136 + nl] = f2bf(val);
                    }
        } else {
            #pragma unroll
            for (int mi = 0; mi < 4; mi++)
                #pragma unroll
                for (int ni = 0; ni < 4; ni++) {
                    int nl = wn + ni * 16 + l15;
                    int m0 = wm + mi * 16 + quad * 4;
                    s4v o;
                    #pragma unroll
                    for (int r = 0; r < 4; r++)
                        o[r] = (short)f2bf(acc[mi][ni][r] + bias[bn + nl]);
                    *(s4v*)&Cs[nl * 136 + m0] = o;
                }
        }
        __syncthreads();
        #pragma unroll
        for (int it = 0; it < 8; it++) {
            int idx = t + it * 256;
            int rr = idx >> 4, cc = (idx & 15) * 8;
            if (MODE == 1) {
                int m = bm + rr, n = bn + cc;
                int b = m >> 11, s = m & (SEQ - 1);
                int h = n >> 6, dk = n & 63;
                *(s8v*)&((unsigned short*)outp)[(((size_t)(b * NH + h)) * SEQ + s) * 64 + dk] =
                    *(const s8v*)&Cs[rr * 136 + cc];
            } else {
                int n = bn + rr, m0 = bm + cc;
                int b = m0 >> 11, s = m0 & (SEQ - 1);
                int h = n >> 6, dk = n & 63;
                *(s8v*)&((unsigned short*)outp)[((size_t)(b * NH + h) * 64 + dk) * SEQ + s] =
                    *(const s8v*)&Cs[rr * 136 + cc];
            }
        }
    }
}

// XCD-aware bijective swizzle for an (NX x NY) grid dispatched x-fastest.
template<int NX, int NWG>
__device__ __forceinline__ void xcd_swizzle(int& bx, int& by) {
    const int lin = by * NX + bx;
    const int lin2 = (lin & 7) * (NWG >> 3) + (lin >> 3);
    bx = lin2 % NX;
    by = lin2 / NX;
}

// 3 projection GEMMs in one launch (z selects q/k/v); V stored transposed (MODE 2)
__global__ __launch_bounds__(256)
void qkv_gemm(const unsigned short* __restrict__ qb, const unsigned short* __restrict__ kb,
              const unsigned short* __restrict__ vb,
              const unsigned short* __restrict__ WqT, const unsigned short* __restrict__ WkT,
              const unsigned short* __restrict__ WvT,
              const float* __restrict__ bq, const float* __restrict__ bk,
              const float* __restrict__ bv,
              unsigned short* __restrict__ qp, unsigned short* __restrict__ kp,
              unsigned short* __restrict__ vpT)
{
    int bx = blockIdx.x, by = blockIdx.y;
    xcd_swizzle<8, 512>(bx, by);   // cluster same-A-panel blocks per XCD L2
    const int z = blockIdx.z;
    if (z == 0) {
        // fold 1/sqrt(64) AND log2(e) into Q so attention uses exp2 directly
        gemm_core<1>(qb, WqT, bq, qp, 0.18033688011112042f, bx, by);
    } else if (z == 1) {
        gemm_core<1>(kb, WkT, bk, kp, 1.0f, bx, by);
    } else {
        gemm_core<2>(vb, WvT, bv, vpT, 1.0f, bx, by);
    }
}

__global__ __launch_bounds__(256)
void out_gemm(const unsigned short* __restrict__ A, const unsigned short* __restrict__ BT,
              const float* __restrict__ bias, float* __restrict__ outp)
{
    int bx = blockIdx.x, by = blockIdx.y;
    xcd_swizzle<8, 512>(bx, by);
    gemm_core<0>(A, BT, bias, outp, 1.0f, bx, by);
}

// ---------------- MFMA flash attention v11 ----------------
// = r8 body with ONE structural change: K/V double-buffered LDS, ONE barrier per
// tile (was two). Ordering proof: at barrier N every wave finished reading buf[c]
// (PV precedes its barrier arrival) and finished writing buf[c^1]; post-barrier,
// reads of buf[c^1] and writes of buf[c] are both safe. T14 prefetch preserved:
// global->reg loads at loop top are consumed by the ds_write just before the
// barrier, so the barrier's implicit vmcnt(0) is ~free. P-scratch fence and all
// layout math byte-identical to the r6-proven version.
__global__ __launch_bounds__(256)
void attn_mfma(const unsigned short* __restrict__ Q,
               const unsigned short* __restrict__ Kp,
               const unsigned short* __restrict__ VT,
               unsigned short* __restrict__ AO)
{
    __shared__ __align__(16) unsigned short Ks[2][64 * 72];  // [buf][key][d]
    __shared__ __align__(16) unsigned short Vs[2][64 * 72];  // [buf][d][key]
    __shared__ __align__(16) unsigned short Ps[4][32 * 72];  // per-wave P [q][key]
    const int t = threadIdx.x;
    const int lane = t & 63, w = t >> 6;
    const int l15 = lane & 15, quad = lane >> 4;

    int bxs = blockIdx.x, bys = blockIdx.y;
    xcd_swizzle<16, 1024>(bxs, bys);   // 8 heads (4 MB K/V) per XCD L2
    const int bh = bys, q0 = bxs * 128;

    const unsigned short* qbase = Q + ((size_t)bh * SEQ + q0 + w * 32) * 64;
    const unsigned short* kbase = Kp + (size_t)bh * SEQ * 64;
    const unsigned short* vtbase = VT + (size_t)bh * 64 * SEQ;

    // Q B-frags: B[n=l15 -> q=qs*16+l15][k=kc*32+quad*8+j -> d]
    s8v qf[2][2];
    #pragma unroll
    for (int qs = 0; qs < 2; qs++)
        #pragma unroll
        for (int kc = 0; kc < 2; kc++)
            qf[qs][kc] = *(const s8v*)&qbase[(qs * 16 + l15) * 64 + kc * 32 + quad * 8];

    f4v o_acc[2][4];   // [qs][df]
    #pragma unroll
    for (int qs = 0; qs < 2; qs++)
        #pragma unroll
        for (int df = 0; df < 4; df++) o_acc[qs][df] = (f4v){0.f, 0.f, 0.f, 0.f};
    f4v o_l[2];        // row-sum accumulators (l = P*ones), same D-layout as o_acc
    o_l[0] = (f4v){0.f, 0.f, 0.f, 0.f};
    o_l[1] = (f4v){0.f, 0.f, 0.f, 0.f};
    const s8v ones = {0x3F80, 0x3F80, 0x3F80, 0x3F80, 0x3F80, 0x3F80, 0x3F80, 0x3F80};

    const int srow = t >> 3, scol = (t & 7) * 8;
    unsigned short* Pw = (unsigned short*)Ps[w];

    // prologue: stage tile 0 into buf 0 (reg round-trip)
    s8v kreg[2], vreg[2];
    #pragma unroll
    for (int i = 0; i < 2; i++) {
        int row = srow + i * 32;
        kreg[i] = *(const s8v*)&kbase[(size_t)row * 64 + scol];
        vreg[i] = *(const s8v*)&vtbase[(size_t)row * SEQ + scol];
    }
    #pragma unroll
    for (int i = 0; i < 2; i++) {
        int row = srow + i * 32;
        *(s8v*)&Ks[0][row * 72 + scol] = kreg[i];
        *(s8v*)&Vs[0][row * 72 + scol] = vreg[i];
    }
    __syncthreads();

    for (int kt = 0; kt < 32; kt++) {
        const unsigned short* Kc = Ks[kt & 1];
        const unsigned short* Vc = Vs[kt & 1];
        unsigned short* Kn = Ks[(kt + 1) & 1];
        unsigned short* Vn = Vs[(kt + 1) & 1];

        // issue next-tile loads NOW; consumed by the ds_write just before the barrier.
        if (kt < 31) {
            #pragma unroll
            for (int i = 0; i < 2; i++) {
                int row = srow + i * 32;
                kreg[i] = *(const s8v*)&kbase[((size_t)((kt + 1) * 64 + row)) * 64 + scol];
                vreg[i] = *(const s8v*)&vtbase[(size_t)row * SEQ + (kt + 1) * 64 + scol];
            }
        }

        // S^T = K*Q^T: A=kf (m=key), B=qf (n=q). Each kf read serves both q-slices.
        f4v s_acc[2][4];   // [qs][mf]: S^T[key=mf*16+quad*4+r][q=qs*16+l15]
        #pragma unroll
        for (int qs = 0; qs < 2; qs++)
            #pragma unroll
            for (int mf = 0; mf < 4; mf++) s_acc[qs][mf] = (f4v){0.f, 0.f, 0.f, 0.f};
        __builtin_amdgcn_s_setprio(1);
        #pragma unroll
        for (int kc = 0; kc < 2; kc++) {
            const int ko = kc * 32 + quad * 8;
            #pragma unroll
            for (int mf = 0; mf < 4; mf++) {
                s8v kf = *(const s8v*)&Kc[(mf * 16 + l15) * 72 + ko];
                #pragma unroll
                for (int qs = 0; qs < 2; qs++)
                    s_acc[qs][mf] = __builtin_amdgcn_mfma_f32_16x16x32_bf16(
                        kf, qf[qs][kc], s_acc[qs][mf], 0, 0, 0);
            }
        }
        __builtin_amdgcn_s_setprio(0);

        // hardware exp2 + pack; P stored as b64 through a SHORT-vector type so the
        // stores alias the s8v fragment reads under TBAA.
        #pragma unroll
        for (int qs = 0; qs < 2; qs++) {
            #pragma unroll
            for (int mf = 0; mf < 4; mf++) {
                float p0 = __builtin_amdgcn_exp2f(s_acc[qs][mf][0]);
                float p1 = __builtin_amdgcn_exp2f(s_acc[qs][mf][1]);
                float p2 = __builtin_amdgcn_exp2f(s_acc[qs][mf][2]);
                float p3 = __builtin_amdgcn_exp2f(s_acc[qs][mf][3]);
                uint2 pk;
                pk.x = cvt_pk_bf16(p0, p1);
                pk.y = cvt_pk_bf16(p2, p3);
                *(s4v*)&Pw[(qs * 16 + l15) * 72 + mf * 16 + quad * 4] =
                    __builtin_bit_cast(s4v, pk);
            }
        }

        // FENCE: no PV-phase ds_read of P may move above the P ds_writes.
        asm volatile("" ::: "memory");
        __builtin_amdgcn_sched_barrier(0);

        // O += P*V; l += P*1 (row-sum on the MFMA pipe). Same-wave LDS ordered.
        #pragma unroll
        for (int kc2 = 0; kc2 < 2; kc2++) {
            const int ko = kc2 * 32 + quad * 8;
            s8v pf0 = *(const s8v*)&Pw[(0 * 16 + l15) * 72 + ko];
            s8v pf1 = *(const s8v*)&Pw[(1 * 16 + l15) * 72 + ko];
            __builtin_amdgcn_s_setprio(1);
            o_l[0] = __builtin_amdgcn_mfma_f32_16x16x32_bf16(pf0, ones, o_l[0], 0, 0, 0);
            o_l[1] = __builtin_amdgcn_mfma_f32_16x16x32_bf16(pf1, ones, o_l[1], 0, 0, 0);
            #pragma unroll
            for (int df = 0; df < 4; df++) {
                s8v vf = *(const s8v*)&Vc[(df * 16 + l15) * 72 + ko];
                o_acc[0][df] = __builtin_amdgcn_mfma_f32_16x16x32_bf16(pf0, vf, o_acc[0][df], 0, 0, 0);
                o_acc[1][df] = __builtin_amdgcn_mfma_f32_16x16x32_bf16(pf1, vf, o_acc[1][df], 0, 0, 0);
            }
            __builtin_amdgcn_s_setprio(0);
        }

        // write next tile into the OTHER buffer (read 2 tiles ago; all reads of it
        // completed before the previous barrier), then ONE barrier.
        if (kt < 31) {
            #pragma unroll
            for (int i = 0; i < 2; i++) {
                int row = srow + i * 32;
                *(s8v*)&Kn[row * 72 + scol] = kreg[i];
                *(s8v*)&Vn[row * 72 + scol] = vreg[i];
            }
        }
        __syncthreads();
    }

    // o_l[qs][r] is the full row-sum for q = qs*16 + quad*4 + r -- exactly o_acc's
    // row layout, so the divide needs no cross-lane movement.
    const int b = bh >> 4, h = bh & (NH - 1);
    #pragma unroll
    for (int qs = 0; qs < 2; qs++) {
        #pragma unroll
        for (int r = 0; r < 4; r++) {
            float lq = 1.0f / o_l[qs][r];
            int s = q0 + w * 32 + qs * 16 + quad * 4 + r;
            #pragma unroll
            for (int df = 0; df < 4; df++)
                AO[((size_t)(b * SEQ + s)) * DIM + h * 64 + df * 16 + l15] =
                    f2bf(o_acc[qs][df][r] * lq);
        }
    }
}

extern "C" void kernel_launch(void* const* d_in, const int* in_sizes, int n_in,
                              void* d_out, int out_size, void* d_ws, size_t ws_size,
                              hipStream_t stream) {
    const float* q  = (const float*)d_in[0];
    const float* k  = (const float*)d_in[1];
    const float* v  = (const float*)d_in[2];
    const float* Wq = (const float*)d_in[3];
    const float* bq = (const float*)d_in[4];
    const float* Wk = (const float*)d_in[5];
    const float* bk = (const float*)d_in[6];
    const float* Wv = (const float*)d_in[7];
    const float* bv = (const float*)d_in[8];
    const float* Wo = (const float*)d_in[9];
    const float* bo = (const float*)d_in[10];
    float* out = (float*)d_out;

    const size_t MK = (size_t)4 * SEQ * DIM;   // 8M elements
    const size_t WK = (size_t)DIM * DIM;
    unsigned short* wsu = (unsigned short*)d_ws;
    unsigned short* qb  = wsu;
    unsigned short* kb  = qb + MK;
    unsigned short* vb  = kb + MK;
    unsigned short* WqT = vb + MK;
    unsigned short* WkT = WqT + WK;
    unsigned short* WvT = WkT + WK;
    unsigned short* WoT = WvT + WK;
    unsigned short* qp  = WoT + WK;            // bf16 [64][2048][64], pre-scaled log2e/8
    unsigned short* kp  = qp + MK;
    unsigned short* vpT = kp + MK;             // bf16 [64][64][2048] (transposed V, fused)
    unsigned short* ao  = vpT + MK;

    const int n4 = (int)(MK / 4);
    conv_all<<<dim3((n4 + 255) / 256, 4), 256, 0, stream>>>(
        q, k, v, qb, kb, vb, n4, Wq, Wk, Wv, Wo, WqT, WkT, WvT, WoT);

    qkv_gemm<<<dim3(DIM / 128, (4 * SEQ) / 128, 3), 256, 0, stream>>>(
        qb, kb, vb, WqT, WkT, WvT, bq, bk, bv, qp, kp, vpT);

    attn_mfma<<<dim3(SEQ / 128, 4 * NH), 256, 0, stream>>>(qp, kp, vpT, ao);

    out_gemm<<<dim3(DIM / 128, (4 * SEQ) / 128), 256, 0, stream>>>(ao, WoT, bo, out);
}

// Round 10
// 356.827 us; speedup vs baseline: 1.0328x; 1.0328x over previous
//
#include <hip/hip_runtime.h>
#include <math.h>

#define SEQ 2048
#define DIM 1024
#define NH 16

typedef short s8v __attribute__((ext_vector_type(8)));
typedef short s4v __attribute__((ext_vector_type(4)));
typedef float f4v __attribute__((ext_vector_type(4)));

__device__ __forceinline__ unsigned short f2bf(float x) {   // RNE
    unsigned u = __float_as_uint(x);
    u += 0x7FFFu + ((u >> 16) & 1u);
    return (unsigned short)(u >> 16);
}
__device__ __forceinline__ unsigned cvt_pk_bf16(float lo, float hi) {
    unsigned r;
    asm("v_cvt_pk_bf16_f32 %0, %1, %2" : "=v"(r) : "v"(lo), "v"(hi));
    return r;
}

// ---------------- fused: q,k,v fp32->bf16  AND  4x W transpose->bf16 ----------------
__global__ __launch_bounds__(256)
void conv_all(const float* __restrict__ q, const float* __restrict__ k,
              const float* __restrict__ v,
              unsigned short* __restrict__ qb, unsigned short* __restrict__ kb,
              unsigned short* __restrict__ vb, int n4,
              const float* __restrict__ W0, const float* __restrict__ W1,
              const float* __restrict__ W2, const float* __restrict__ W3,
              unsigned short* __restrict__ T0, unsigned short* __restrict__ T1,
              unsigned short* __restrict__ T2, unsigned short* __restrict__ T3)
{
    __shared__ float T[64][65];
    const int t = threadIdx.x;
    if (blockIdx.y < 3) {
        const float* in = (blockIdx.y == 0) ? q : (blockIdx.y == 1) ? k : v;
        unsigned short* out = (blockIdx.y == 0) ? qb : (blockIdx.y == 1) ? kb : vb;
        int i = blockIdx.x * 256 + t;
        if (i >= n4) return;
        float4 x = ((const float4*)in)[i];
        ushort4 o;
        o.x = f2bf(x.x); o.y = f2bf(x.y); o.z = f2bf(x.z); o.w = f2bf(x.w);
        ((ushort4*)out)[i] = o;
        return;
    }
    int id = blockIdx.x;
    if (id >= 1024) return;
    const int wz = id >> 8, rem = id & 255;
    const int bxx = rem & 15, byy = rem >> 4;
    const float* W = (wz == 0) ? W0 : (wz == 1) ? W1 : (wz == 2) ? W2 : W3;
    unsigned short* WT = (wz == 0) ? T0 : (wz == 1) ? T1 : (wz == 2) ? T2 : T3;
    const int n0 = bxx * 64, k0 = byy * 64;
    #pragma unroll
    for (int i = 0; i < 4; i++) {
        int idx = t + i * 256;
        int r = idx >> 4, c4 = idx & 15;
        float4 vv = *(const float4*)&W[(size_t)(k0 + r) * DIM + n0 + c4 * 4];
        T[r][c4 * 4 + 0] = vv.x; T[r][c4 * 4 + 1] = vv.y;
        T[r][c4 * 4 + 2] = vv.z; T[r][c4 * 4 + 3] = vv.w;
    }
    __syncthreads();
    #pragma unroll
    for (int i = 0; i < 4; i++) {
        int idx = t + i * 256;
        int rn = idx >> 4, c4 = idx & 15;
        ushort4 o;
        o.x = f2bf(T[c4 * 4 + 0][rn]);
        o.y = f2bf(T[c4 * 4 + 1][rn]);
        o.z = f2bf(T[c4 * 4 + 2][rn]);
        o.w = f2bf(T[c4 * 4 + 3][rn]);
        *(ushort4*)&WT[(size_t)(n0 + rn) * DIM + k0 + c4 * 4] = o;
    }
}

// ---------------- GEMM core (m97 staging), shared by qkv+out projections ----------
template<int MODE>
__device__ __forceinline__
void gemm_core(const unsigned short* __restrict__ A,
               const unsigned short* __restrict__ BT,
               const float* __restrict__ bias, void* __restrict__ outp,
               float scale, int bx, int by)
{
    __shared__ __align__(16) unsigned short smem[17408];
    unsigned short* As = smem;
    unsigned short* Bs = smem + 128 * 64;
    const int t = threadIdx.x;
    const int lane = t & 63, w = t >> 6;
    const int l15 = lane & 15, quad = lane >> 4;
    const int bm = by * 128, bn = bx * 128;
    const int wm = (w & 1) * 64, wn = (w >> 1) * 64;
    const int lrow = lane >> 3, lcol = (lane & 7) * 8;

    f4v acc[4][4];
    #pragma unroll
    for (int mi = 0; mi < 4; mi++)
        #pragma unroll
        for (int ni = 0; ni < 4; ni++)
            acc[mi][ni] = (f4v){0.f, 0.f, 0.f, 0.f};

    for (int k0 = 0; k0 < DIM; k0 += 64) {
        __syncthreads();
        #pragma unroll
        for (int i = 0; i < 4; i++) {
            int ci = w + i * 4;
            int row = ci * 8 + lrow;
            __builtin_amdgcn_global_load_lds(
                (const __attribute__((address_space(1))) unsigned int*)
                    (A + (size_t)(bm + row) * DIM + k0 + lcol),
                (__attribute__((address_space(3))) unsigned int*)(As + ci * 8 * 64),
                16, 0, 0);
            __builtin_amdgcn_global_load_lds(
                (const __attribute__((address_space(1))) unsigned int*)
                    (BT + (size_t)(bn + row) * DIM + k0 + lcol),
                (__attribute__((address_space(3))) unsigned int*)(Bs + ci * 8 * 64),
                16, 0, 0);
        }
        __syncthreads();
        #pragma unroll
        for (int kc = 0; kc < 2; kc++) {
            const int ko = kc * 32 + quad * 8;
            s8v af[4], bf[4];
            #pragma unroll
            for (int mi = 0; mi < 4; mi++)
                af[mi] = *(const s8v*)&As[(wm + mi * 16 + l15) * 64 + ko];
            #pragma unroll
            for (int ni = 0; ni < 4; ni++)
                bf[ni] = *(const s8v*)&Bs[(wn + ni * 16 + l15) * 64 + ko];
            #pragma unroll
            for (int mi = 0; mi < 4; mi++)
                #pragma unroll
                for (int ni = 0; ni < 4; ni++)
                    acc[mi][ni] = __builtin_amdgcn_mfma_f32_16x16x32_bf16(
                        af[mi], bf[ni], acc[mi][ni], 0, 0, 0);
        }
    }

    if (MODE == 0) {
        #pragma unroll
        for (int mi = 0; mi < 4; mi++)
            #pragma unroll
            for (int ni = 0; ni < 4; ni++)
                #pragma unroll
                for (int r = 0; r < 4; r++) {
                    int m = bm + wm + mi * 16 + quad * 4 + r;
                    int n = bn + wn + ni * 16 + l15;
                    ((float*)outp)[(size_t)m * DIM + n] = acc[mi][ni][r] + bias[n];
                }
    } else {
        __syncthreads();
        unsigned short* Cs = smem;    // [128][136] padded bf16 C tile
        if (MODE == 1) {
            #pragma unroll
            for (int mi = 0; mi < 4; mi++)
                #pragma unroll
                for (int ni = 0; ni < 4; ni++)
                    #pragma unroll
                    for (int r = 0; r < 4; r++) {
                        int ml = wm + mi * 16 + quad * 4 + r;
                        int nl = wn + ni * 16 + l15;
                        float val = (acc[mi][ni][r] + bias[bn + nl]) * scale;
                        Cs[ml * 136 + nl] = f2bf(val);
                    }
        } else {
            #pragma unroll
            for (int mi = 0; mi < 4; mi++)
                #pragma unroll
                for (int ni = 0; ni < 4; ni++) {
                    int nl = wn + ni * 16 + l15;
                    int m0 = wm + mi * 16 + quad * 4;
                    s4v o;
                    #pragma unroll
                    for (int r = 0; r < 4; r++)
                        o[r] = (short)f2bf(acc[mi][ni][r] + bias[bn + nl]);
                    *(s4v*)&Cs[nl * 136 + m0] = o;
                }
        }
        __syncthreads();
        #pragma unroll
        for (int it = 0; it < 8; it++) {
            int idx = t + it * 256;
            int rr = idx >> 4, cc = (idx & 15) * 8;
            if (MODE == 1) {
                int m = bm + rr, n = bn + cc;
                int b = m >> 11, s = m & (SEQ - 1);
                int h = n >> 6, dk = n & 63;
                *(s8v*)&((unsigned short*)outp)[(((size_t)(b * NH + h)) * SEQ + s) * 64 + dk] =
                    *(const s8v*)&Cs[rr * 136 + cc];
            } else {
                int n = bn + rr, m0 = bm + cc;
                int b = m0 >> 11, s = m0 & (SEQ - 1);
                int h = n >> 6, dk = n & 63;
                *(s8v*)&((unsigned short*)outp)[((size_t)(b * NH + h) * 64 + dk) * SEQ + s] =
                    *(const s8v*)&Cs[rr * 136 + cc];
            }
        }
    }
}

// XCD-aware bijective swizzle for an (NX x NY) grid dispatched x-fastest.
template<int NX, int NWG>
__device__ __forceinline__ void xcd_swizzle(int& bx, int& by) {
    const int lin = by * NX + bx;
    const int lin2 = (lin & 7) * (NWG >> 3) + (lin >> 3);
    bx = lin2 % NX;
    by = lin2 / NX;
}

__global__ __launch_bounds__(256)
void qkv_gemm(const unsigned short* __restrict__ qb, const unsigned short* __restrict__ kb,
              const unsigned short* __restrict__ vb,
              const unsigned short* __restrict__ WqT, const unsigned short* __restrict__ WkT,
              const unsigned short* __restrict__ WvT,
              const float* __restrict__ bq, const float* __restrict__ bk,
              const float* __restrict__ bv,
              unsigned short* __restrict__ qp, unsigned short* __restrict__ kp,
              unsigned short* __restrict__ vpT)
{
    int bx = blockIdx.x, by = blockIdx.y;
    xcd_swizzle<8, 512>(bx, by);
    const int z = blockIdx.z;
    if (z == 0) {
        gemm_core<1>(qb, WqT, bq, qp, 0.18033688011112042f, bx, by);
    } else if (z == 1) {
        gemm_core<1>(kb, WkT, bk, kp, 1.0f, bx, by);
    } else {
        gemm_core<2>(vb, WvT, bv, vpT, 1.0f, bx, by);
    }
}

__global__ __launch_bounds__(256)
void out_gemm(const unsigned short* __restrict__ A, const unsigned short* __restrict__ BT,
              const float* __restrict__ bias, float* __restrict__ outp)
{
    int bx = blockIdx.x, by = blockIdx.y;
    xcd_swizzle<8, 512>(bx, by);
    gemm_core<0>(A, BT, bias, outp, 1.0f, bx, by);
}

// ---------------- MFMA flash attention v12: T15 att[2] pipeline ----------------
// Per iteration: QK(kt) -> s_cur (MFMA pipe) runs INDEPENDENT of exp+pack+PV of
// tile kt-1 from s_prev (VALU pipe) -> scheduler overlaps them. 2-barrier r8
// skeleton; dbuf parity: write(tile kt+1 -> buf (kt+1)&1) happens after barrier-1,
// by which point all waves' PV(kt-1) reads of that buffer are complete.
// s_cur/s_prev statically named (sA/sB) via peel + unroll-2 (no runtime reg idx).
// P-store fence, P layout, ones-MFMA row-sum byte-identical to r6-proven code.
__global__ __launch_bounds__(256)
void attn_mfma(const unsigned short* __restrict__ Q,
               const unsigned short* __restrict__ Kp,
               const unsigned short* __restrict__ VT,
               unsigned short* __restrict__ AO)
{
    __shared__ __align__(16) unsigned short Ks[2][64 * 72];  // [buf][key][d]
    __shared__ __align__(16) unsigned short Vs[2][64 * 72];  // [buf][d][key]
    __shared__ __align__(16) unsigned short Ps[4][32 * 72];  // per-wave P [q][key]
    const int t = threadIdx.x;
    const int lane = t & 63, w = t >> 6;
    const int l15 = lane & 15, quad = lane >> 4;

    int bxs = blockIdx.x, bys = blockIdx.y;
    xcd_swizzle<16, 1024>(bxs, bys);   // 8 heads (4 MB K/V) per XCD L2
    const int bh = bys, q0 = bxs * 128;

    const unsigned short* qbase = Q + ((size_t)bh * SEQ + q0 + w * 32) * 64;
    const unsigned short* kbase = Kp + (size_t)bh * SEQ * 64;
    const unsigned short* vtbase = VT + (size_t)bh * 64 * SEQ;

    s8v qf[2][2];
    #pragma unroll
    for (int qs = 0; qs < 2; qs++)
        #pragma unroll
        for (int kc = 0; kc < 2; kc++)
            qf[qs][kc] = *(const s8v*)&qbase[(qs * 16 + l15) * 64 + kc * 32 + quad * 8];

    f4v o_acc[2][4];
    #pragma unroll
    for (int qs = 0; qs < 2; qs++)
        #pragma unroll
        for (int df = 0; df < 4; df++) o_acc[qs][df] = (f4v){0.f, 0.f, 0.f, 0.f};
    f4v o_l[2];
    o_l[0] = (f4v){0.f, 0.f, 0.f, 0.f};
    o_l[1] = (f4v){0.f, 0.f, 0.f, 0.f};
    const s8v ones = {0x3F80, 0x3F80, 0x3F80, 0x3F80, 0x3F80, 0x3F80, 0x3F80, 0x3F80};

    const int srow = t >> 3, scol = (t & 7) * 8;
    unsigned short* Pw = (unsigned short*)Ps[w];

    s8v kreg[2], vreg[2];
    f4v sA[2][4], sB[2][4];

    // --- helpers (inlined lambdas; all register indices compile-time) ---
    auto qk_into = [&](int kt, int bufc, f4v (&scur)[2][4]) {
        #pragma unroll
        for (int qs = 0; qs < 2; qs++)
            #pragma unroll
            for (int mf = 0; mf < 4; mf++) scur[qs][mf] = (f4v){0.f, 0.f, 0.f, 0.f};
        __builtin_amdgcn_s_setprio(1);
        #pragma unroll
        for (int kc = 0; kc < 2; kc++) {
            const int ko = kc * 32 + quad * 8;
            #pragma unroll
            for (int mf = 0; mf < 4; mf++) {
                s8v kf = *(const s8v*)&Ks[bufc][(mf * 16 + l15) * 72 + ko];
                scur[0][mf] = __builtin_amdgcn_mfma_f32_16x16x32_bf16(kf, qf[0][kc], scur[0][mf], 0, 0, 0);
                scur[1][mf] = __builtin_amdgcn_mfma_f32_16x16x32_bf16(kf, qf[1][kc], scur[1][mf], 0, 0, 0);
            }
        }
        __builtin_amdgcn_s_setprio(0);
        (void)kt;
    };
    auto exp_pv_prev = [&](f4v (&sprev)[2][4], int bufp) {
        // exp2 + pack of the PREVIOUS tile's scores; P via short-typed stores (TBAA).
        #pragma unroll
        for (int qs = 0; qs < 2; qs++) {
            #pragma unroll
            for (int mf = 0; mf < 4; mf++) {
                float p0 = __builtin_amdgcn_exp2f(sprev[qs][mf][0]);
                float p1 = __builtin_amdgcn_exp2f(sprev[qs][mf][1]);
                float p2 = __builtin_amdgcn_exp2f(sprev[qs][mf][2]);
                float p3 = __builtin_amdgcn_exp2f(sprev[qs][mf][3]);
                uint2 pk;
                pk.x = cvt_pk_bf16(p0, p1);
                pk.y = cvt_pk_bf16(p2, p3);
                *(s4v*)&Pw[(qs * 16 + l15) * 72 + mf * 16 + quad * 4] =
                    __builtin_bit_cast(s4v, pk);
            }
        }
        // FENCE: no PV-phase ds_read of P may move above the P ds_writes.
        asm volatile("" ::: "memory");
        __builtin_amdgcn_sched_barrier(0);
        #pragma unroll
        for (int kc2 = 0; kc2 < 2; kc2++) {
            const int ko = kc2 * 32 + quad * 8;
            s8v pf0 = *(const s8v*)&Pw[(0 * 16 + l15) * 72 + ko];
            s8v pf1 = *(const s8v*)&Pw[(1 * 16 + l15) * 72 + ko];
            __builtin_amdgcn_s_setprio(1);
            o_l[0] = __builtin_amdgcn_mfma_f32_16x16x32_bf16(pf0, ones, o_l[0], 0, 0, 0);
            o_l[1] = __builtin_amdgcn_mfma_f32_16x16x32_bf16(pf1, ones, o_l[1], 0, 0, 0);
            #pragma unroll
            for (int df = 0; df < 4; df++) {
                s8v vf = *(const s8v*)&Vs[bufp][(df * 16 + l15) * 72 + ko];
                o_acc[0][df] = __builtin_amdgcn_mfma_f32_16x16x32_bf16(pf0, vf, o_acc[0][df], 0, 0, 0);
                o_acc[1][df] = __builtin_amdgcn_mfma_f32_16x16x32_bf16(pf1, vf, o_acc[1][df], 0, 0, 0);
            }
            __builtin_amdgcn_s_setprio(0);
        }
    };
    auto load_tile = [&](int kt1) {   // global -> regs for tile kt1
        #pragma unroll
        for (int i = 0; i < 2; i++) {
            int row = srow + i * 32;
            kreg[i] = *(const s8v*)&kbase[((size_t)(kt1 * 64 + row)) * 64 + scol];
            vreg[i] = *(const s8v*)&vtbase[(size_t)row * SEQ + kt1 * 64 + scol];
        }
    };
    auto write_tile = [&](int buf) {  // regs -> LDS buf
        #pragma unroll
        for (int i = 0; i < 2; i++) {
            int row = srow + i * 32;
            *(s8v*)&Ks[buf][row * 72 + scol] = kreg[i];
            *(s8v*)&Vs[buf][row * 72 + scol] = vreg[i];
        }
    };

    // prologue: stage tile 0 into buf 0
    load_tile(0);
    write_tile(0);
    __syncthreads();

    // kt = 0: QK(0) -> sA; no prev; write tile1 -> buf1
    load_tile(1);
    qk_into(0, 0, sA);
    __syncthreads();
    write_tile(1);
    __syncthreads();

    // pairs kt = 1..30
    for (int kt = 1; kt < 31; kt += 2) {
        // odd kt: QK(kt)->sB from buf1; exp+PV(kt-1) from sA, V buf0; write kt+1 -> buf0
        load_tile(kt + 1);
        qk_into(kt, 1, sB);
        exp_pv_prev(sA, 0);
        __syncthreads();           // all PV(kt-1) reads of buf0 done
        write_tile(0);             // tile kt+1 -> buf0
        __syncthreads();           // visible for next QK

        // even kt+1: QK(kt+1)->sA from buf0; exp+PV(kt) from sB, V buf1; write kt+2 -> buf1
        load_tile(kt + 2);
        qk_into(kt + 1, 0, sA);
        exp_pv_prev(sB, 1);
        __syncthreads();
        write_tile(1);             // tile kt+2 -> buf1
        __syncthreads();
    }

    // kt = 31: QK(31)->sB from buf1; exp+PV(30) from sA, V buf0; no more staging
    qk_into(31, 1, sB);
    exp_pv_prev(sA, 0);
    // tail: exp+PV(31) from sB, V buf1 (no writes remain; same-wave LDS ordering only)
    exp_pv_prev(sB, 1);

    const int b = bh >> 4, h = bh & (NH - 1);
    #pragma unroll
    for (int qs = 0; qs < 2; qs++) {
        #pragma unroll
        for (int r = 0; r < 4; r++) {
            float lq = 1.0f / o_l[qs][r];
            int s = q0 + w * 32 + qs * 16 + quad * 4 + r;
            #pragma unroll
            for (int df = 0; df < 4; df++)
                AO[((size_t)(b * SEQ + s)) * DIM + h * 64 + df * 16 + l15] =
                    f2bf(o_acc[qs][df][r] * lq);
        }
    }
}

extern "C" void kernel_launch(void* const* d_in, const int* in_sizes, int n_in,
                              void* d_out, int out_size, void* d_ws, size_t ws_size,
                              hipStream_t stream) {
    const float* q  = (const float*)d_in[0];
    const float* k  = (const float*)d_in[1];
    const float* v  = (const float*)d_in[2];
    const float* Wq = (const float*)d_in[3];
    const float* bq = (const float*)d_in[4];
    const float* Wk = (const float*)d_in[5];
    const float* bk = (const float*)d_in[6];
    const float* Wv = (const float*)d_in[7];
    const float* bv = (const float*)d_in[8];
    const float* Wo = (const float*)d_in[9];
    const float* bo = (const float*)d_in[10];
    float* out = (float*)d_out;

    const size_t MK = (size_t)4 * SEQ * DIM;   // 8M elements
    const size_t WK = (size_t)DIM * DIM;
    unsigned short* wsu = (unsigned short*)d_ws;
    unsigned short* qb  = wsu;
    unsigned short* kb  = qb + MK;
    unsigned short* vb  = kb + MK;
    unsigned short* WqT = vb + MK;
    unsigned short* WkT = WqT + WK;
    unsigned short* WvT = WkT + WK;
    unsigned short* WoT = WvT + WK;
    unsigned short* qp  = WoT + WK;            // bf16 [64][2048][64], pre-scaled log2e/8
    unsigned short* kp  = qp + MK;
    unsigned short* vpT = kp + MK;             // bf16 [64][64][2048] (transposed V, fused)
    unsigned short* ao  = vpT + MK;

    const int n4 = (int)(MK / 4);
    conv_all<<<dim3((n4 + 255) / 256, 4), 256, 0, stream>>>(
        q, k, v, qb, kb, vb, n4, Wq, Wk, Wv, Wo, WqT, WkT, WvT, WoT);

    qkv_gemm<<<dim3(DIM / 128, (4 * SEQ) / 128, 3), 256, 0, stream>>>(
        qb, kb, vb, WqT, WkT, WvT, bq, bk, bv, qp, kp, vpT);

    attn_mfma<<<dim3(SEQ / 128, 4 * NH), 256, 0, stream>>>(qp, kp, vpT, ao);

    out_gemm<<<dim3(DIM / 128, (4 * SEQ) / 128), 256, 0, stream>>>(ao, WoT, bo, out);
}

// Round 11
// 343.002 us; speedup vs baseline: 1.0744x; 1.0403x over previous
//
#include <hip/hip_runtime.h>
#include <math.h>

#define SEQ 2048
#define DIM 1024
#define NH 16

typedef short s8v __attribute__((ext_vector_type(8)));
typedef short s4v __attribute__((ext_vector_type(4)));
typedef float f4v __attribute__((ext_vector_type(4)));

__device__ __forceinline__ unsigned short f2bf(float x) {   // RNE
    unsigned u = __float_as_uint(x);
    u += 0x7FFFu + ((u >> 16) & 1u);
    return (unsigned short)(u >> 16);
}
__device__ __forceinline__ unsigned cvt_pk_bf16(float lo, float hi) {
    unsigned r;
    asm("v_cvt_pk_bf16_f32 %0, %1, %2" : "=v"(r) : "v"(lo), "v"(hi));
    return r;
}

// ---------------- fused: q,k,v fp32->bf16  AND  4x W transpose->bf16 ----------------
__global__ __launch_bounds__(256)
void conv_all(const float* __restrict__ q, const float* __restrict__ k,
              const float* __restrict__ v,
              unsigned short* __restrict__ qb, unsigned short* __restrict__ kb,
              unsigned short* __restrict__ vb, int n4,
              const float* __restrict__ W0, const float* __restrict__ W1,
              const float* __restrict__ W2, const float* __restrict__ W3,
              unsigned short* __restrict__ T0, unsigned short* __restrict__ T1,
              unsigned short* __restrict__ T2, unsigned short* __restrict__ T3)
{
    __shared__ float T[64][65];
    const int t = threadIdx.x;
    if (blockIdx.y < 3) {
        const float* in = (blockIdx.y == 0) ? q : (blockIdx.y == 1) ? k : v;
        unsigned short* out = (blockIdx.y == 0) ? qb : (blockIdx.y == 1) ? kb : vb;
        int i = blockIdx.x * 256 + t;
        if (i >= n4) return;
        float4 x = ((const float4*)in)[i];
        ushort4 o;
        o.x = f2bf(x.x); o.y = f2bf(x.y); o.z = f2bf(x.z); o.w = f2bf(x.w);
        ((ushort4*)out)[i] = o;
        return;
    }
    int id = blockIdx.x;
    if (id >= 1024) return;
    const int wz = id >> 8, rem = id & 255;
    const int bxx = rem & 15, byy = rem >> 4;
    const float* W = (wz == 0) ? W0 : (wz == 1) ? W1 : (wz == 2) ? W2 : W3;
    unsigned short* WT = (wz == 0) ? T0 : (wz == 1) ? T1 : (wz == 2) ? T2 : T3;
    const int n0 = bxx * 64, k0 = byy * 64;
    #pragma unroll
    for (int i = 0; i < 4; i++) {
        int idx = t + i * 256;
        int r = idx >> 4, c4 = idx & 15;
        float4 vv = *(const float4*)&W[(size_t)(k0 + r) * DIM + n0 + c4 * 4];
        T[r][c4 * 4 + 0] = vv.x; T[r][c4 * 4 + 1] = vv.y;
        T[r][c4 * 4 + 2] = vv.z; T[r][c4 * 4 + 3] = vv.w;
    }
    __syncthreads();
    #pragma unroll
    for (int i = 0; i < 4; i++) {
        int idx = t + i * 256;
        int rn = idx >> 4, c4 = idx & 15;
        ushort4 o;
        o.x = f2bf(T[c4 * 4 + 0][rn]);
        o.y = f2bf(T[c4 * 4 + 1][rn]);
        o.z = f2bf(T[c4 * 4 + 2][rn]);
        o.w = f2bf(T[c4 * 4 + 3][rn]);
        *(ushort4*)&WT[(size_t)(n0 + rn) * DIM + k0 + c4 * 4] = o;
    }
}

// ---------------- GEMM core (m97 staging), shared by qkv+out projections ----------
template<int MODE>
__device__ __forceinline__
void gemm_core(const unsigned short* __restrict__ A,
               const unsigned short* __restrict__ BT,
               const float* __restrict__ bias, void* __restrict__ outp,
               float scale, int bx, int by)
{
    __shared__ __align__(16) unsigned short smem[17408];
    unsigned short* As = smem;
    unsigned short* Bs = smem + 128 * 64;
    const int t = threadIdx.x;
    const int lane = t & 63, w = t >> 6;
    const int l15 = lane & 15, quad = lane >> 4;
    const int bm = by * 128, bn = bx * 128;
    const int wm = (w & 1) * 64, wn = (w >> 1) * 64;
    const int lrow = lane >> 3, lcol = (lane & 7) * 8;

    f4v acc[4][4];
    #pragma unroll
    for (int mi = 0; mi < 4; mi++)
        #pragma unroll
        for (int ni = 0; ni < 4; ni++)
            acc[mi][ni] = (f4v){0.f, 0.f, 0.f, 0.f};

    for (int k0 = 0; k0 < DIM; k0 += 64) {
        __syncthreads();
        #pragma unroll
        for (int i = 0; i < 4; i++) {
            int ci = w + i * 4;
            int row = ci * 8 + lrow;
            __builtin_amdgcn_global_load_lds(
                (const __attribute__((address_space(1))) unsigned int*)
                    (A + (size_t)(bm + row) * DIM + k0 + lcol),
                (__attribute__((address_space(3))) unsigned int*)(As + ci * 8 * 64),
                16, 0, 0);
            __builtin_amdgcn_global_load_lds(
                (const __attribute__((address_space(1))) unsigned int*)
                    (BT + (size_t)(bn + row) * DIM + k0 + lcol),
                (__attribute__((address_space(3))) unsigned int*)(Bs + ci * 8 * 64),
                16, 0, 0);
        }
        __syncthreads();
        #pragma unroll
        for (int kc = 0; kc < 2; kc++) {
            const int ko = kc * 32 + quad * 8;
            s8v af[4], bf[4];
            #pragma unroll
            for (int mi = 0; mi < 4; mi++)
                af[mi] = *(const s8v*)&As[(wm + mi * 16 + l15) * 64 + ko];
            #pragma unroll
            for (int ni = 0; ni < 4; ni++)
                bf[ni] = *(const s8v*)&Bs[(wn + ni * 16 + l15) * 64 + ko];
            #pragma unroll
            for (int mi = 0; mi < 4; mi++)
                #pragma unroll
                for (int ni = 0; ni < 4; ni++)
                    acc[mi][ni] = __builtin_amdgcn_mfma_f32_16x16x32_bf16(
                        af[mi], bf[ni], acc[mi][ni], 0, 0, 0);
        }
    }

    if (MODE == 0) {
        #pragma unroll
        for (int mi = 0; mi < 4; mi++)
            #pragma unroll
            for (int ni = 0; ni < 4; ni++)
                #pragma unroll
                for (int r = 0; r < 4; r++) {
                    int m = bm + wm + mi * 16 + quad * 4 + r;
                    int n = bn + wn + ni * 16 + l15;
                    ((float*)outp)[(size_t)m * DIM + n] = acc[mi][ni][r] + bias[n];
                }
    } else {
        __syncthreads();
        unsigned short* Cs = smem;    // [128][136] padded bf16 C tile
        if (MODE == 1) {
            #pragma unroll
            for (int mi = 0; mi < 4; mi++)
                #pragma unroll
                for (int ni = 0; ni < 4; ni++)
                    #pragma unroll
                    for (int r = 0; r < 4; r++) {
                        int ml = wm + mi * 16 + quad * 4 + r;
                        int nl = wn + ni * 16 + l15;
                        float val = (acc[mi][ni][r] + bias[bn + nl]) * scale;
                        Cs[ml * 136 + nl] = f2bf(val);
                    }
        } else {
            #pragma unroll
            for (int mi = 0; mi < 4; mi++)
                #pragma unroll
                for (int ni = 0; ni < 4; ni++) {
                    int nl = wn + ni * 16 + l15;
                    int m0 = wm + mi * 16 + quad * 4;
                    s4v o;
                    #pragma unroll
                    for (int r = 0; r < 4; r++)
                        o[r] = (short)f2bf(acc[mi][ni][r] + bias[bn + nl]);
                    *(s4v*)&Cs[nl * 136 + m0] = o;
                }
        }
        __syncthreads();
        #pragma unroll
        for (int it = 0; it < 8; it++) {
            int idx = t + it * 256;
            int rr = idx >> 4, cc = (idx & 15) * 8;
            if (MODE == 1) {
                int m = bm + rr, n = bn + cc;
                int b = m >> 11, s = m & (SEQ - 1);
                int h = n >> 6, dk = n & 63;
                *(s8v*)&((unsigned short*)outp)[(((size_t)(b * NH + h)) * SEQ + s) * 64 + dk] =
                    *(const s8v*)&Cs[rr * 136 + cc];
            } else {
                int n = bn + rr, m0 = bm + cc;
                int b = m0 >> 11, s = m0 & (SEQ - 1);
                int h = n >> 6, dk = n & 63;
                *(s8v*)&((unsigned short*)outp)[((size_t)(b * NH + h) * 64 + dk) * SEQ + s] =
                    *(const s8v*)&Cs[rr * 136 + cc];
            }
        }
    }
}

// XCD-aware bijective swizzle for an (NX x NY) grid dispatched x-fastest.
template<int NX, int NWG>
__device__ __forceinline__ void xcd_swizzle(int& bx, int& by) {
    const int lin = by * NX + bx;
    const int lin2 = (lin & 7) * (NWG >> 3) + (lin >> 3);
    bx = lin2 % NX;
    by = lin2 / NX;
}

__global__ __launch_bounds__(256)
void qkv_gemm(const unsigned short* __restrict__ qb, const unsigned short* __restrict__ kb,
              const unsigned short* __restrict__ vb,
              const unsigned short* __restrict__ WqT, const unsigned short* __restrict__ WkT,
              const unsigned short* __restrict__ WvT,
              const float* __restrict__ bq, const float* __restrict__ bk,
              const float* __restrict__ bv,
              unsigned short* __restrict__ qp, unsigned short* __restrict__ kp,
              unsigned short* __restrict__ vpT)
{
    int bx = blockIdx.x, by = blockIdx.y;
    xcd_swizzle<8, 512>(bx, by);
    const int z = blockIdx.z;
    if (z == 0) {
        gemm_core<1>(qb, WqT, bq, qp, 0.18033688011112042f, bx, by);
    } else if (z == 1) {
        gemm_core<1>(kb, WkT, bk, kp, 1.0f, bx, by);
    } else {
        gemm_core<2>(vb, WvT, bv, vpT, 1.0f, bx, by);
    }
}

__global__ __launch_bounds__(256)
void out_gemm(const unsigned short* __restrict__ A, const unsigned short* __restrict__ BT,
              const float* __restrict__ bias, float* __restrict__ outp)
{
    int bx = blockIdx.x, by = blockIdx.y;
    xcd_swizzle<8, 512>(bx, by);
    gemm_core<0>(A, BT, bias, outp, 1.0f, bx, by);
}

// ---------------- MFMA flash attention v13: 64 q-rows per wave ----------------
// LDS-throughput-bound fix (r10 ledger: LDS pipe ~86% busy): each wave reads the
// WHOLE K/V tile from LDS regardless of q-rows owned, so doubling q-rows/wave
// (32 -> 64) halves wave-tiles while K/V-frag reads per wave-tile stay constant
// -> LDS demand -36%. Block = 4 waves x 64q = 256 q-rows; grid 512 blocks.
// Skeleton = r9-proven single-barrier dbuf (T15 dropped: 2x score state would
// spill at ~280 VGPR). P-race fence + short-typed P stores + ones-MFMA row-sum
// + exp2 carried over unchanged; all formulas parameterized qs 2->4, w*32->w*64.
__global__ __launch_bounds__(256, 2)
void attn_mfma(const unsigned short* __restrict__ Q,
               const unsigned short* __restrict__ Kp,
               const unsigned short* __restrict__ VT,
               unsigned short* __restrict__ AO)
{
    __shared__ __align__(16) unsigned short Ks[2][64 * 72];  // [buf][key][d]
    __shared__ __align__(16) unsigned short Vs[2][64 * 72];  // [buf][d][key]
    __shared__ __align__(16) unsigned short Ps[4][64 * 72];  // per-wave P [q=64][key]
    const int t = threadIdx.x;
    const int lane = t & 63, w = t >> 6;
    const int l15 = lane & 15, quad = lane >> 4;

    int bxs = blockIdx.x, bys = blockIdx.y;
    xcd_swizzle<8, 512>(bxs, bys);   // cluster same-head blocks per XCD L2
    const int bh = bys, q0 = bxs * 256;

    const unsigned short* qbase = Q + ((size_t)bh * SEQ + q0 + w * 64) * 64;
    const unsigned short* kbase = Kp + (size_t)bh * SEQ * 64;
    const unsigned short* vtbase = VT + (size_t)bh * 64 * SEQ;

    // Q B-frags: B[n=l15 -> q=qs*16+l15][k=kc*32+quad*8+j -> d], qs = 0..3
    s8v qf[4][2];
    #pragma unroll
    for (int qs = 0; qs < 4; qs++)
        #pragma unroll
        for (int kc = 0; kc < 2; kc++)
            qf[qs][kc] = *(const s8v*)&qbase[(qs * 16 + l15) * 64 + kc * 32 + quad * 8];

    f4v o_acc[4][4];   // [qs][df]
    #pragma unroll
    for (int qs = 0; qs < 4; qs++)
        #pragma unroll
        for (int df = 0; df < 4; df++) o_acc[qs][df] = (f4v){0.f, 0.f, 0.f, 0.f};
    f4v o_l[4];        // row-sum accumulators (l = P*ones), same D-layout as o_acc
    #pragma unroll
    for (int qs = 0; qs < 4; qs++) o_l[qs] = (f4v){0.f, 0.f, 0.f, 0.f};
    const s8v ones = {0x3F80, 0x3F80, 0x3F80, 0x3F80, 0x3F80, 0x3F80, 0x3F80, 0x3F80};

    const int srow = t >> 3, scol = (t & 7) * 8;
    unsigned short* Pw = (unsigned short*)Ps[w];

    // prologue: stage tile 0 into buf 0 (reg round-trip)
    s8v kreg[2], vreg[2];
    #pragma unroll
    for (int i = 0; i < 2; i++) {
        int row = srow + i * 32;
        kreg[i] = *(const s8v*)&kbase[(size_t)row * 64 + scol];
        vreg[i] = *(const s8v*)&vtbase[(size_t)row * SEQ + scol];
    }
    #pragma unroll
    for (int i = 0; i < 2; i++) {
        int row = srow + i * 32;
        *(s8v*)&Ks[0][row * 72 + scol] = kreg[i];
        *(s8v*)&Vs[0][row * 72 + scol] = vreg[i];
    }
    __syncthreads();

    for (int kt = 0; kt < 32; kt++) {
        const unsigned short* Kc = Ks[kt & 1];
        const unsigned short* Vc = Vs[kt & 1];
        unsigned short* Kn = Ks[(kt + 1) & 1];
        unsigned short* Vn = Vs[(kt + 1) & 1];

        // issue next-tile loads NOW; consumed by the ds_write just before the barrier.
        if (kt < 31) {
            #pragma unroll
            for (int i = 0; i < 2; i++) {
                int row = srow + i * 32;
                kreg[i] = *(const s8v*)&kbase[((size_t)((kt + 1) * 64 + row)) * 64 + scol];
                vreg[i] = *(const s8v*)&vtbase[(size_t)row * SEQ + (kt + 1) * 64 + scol];
            }
        }

        // S^T = K*Q^T: A=kf (m=key), B=qf (n=q). Each kf read serves FOUR q-slices.
        f4v s_acc[4][4];   // [qs][mf]: S^T[key=mf*16+quad*4+r][q=qs*16+l15]
        #pragma unroll
        for (int qs = 0; qs < 4; qs++)
            #pragma unroll
            for (int mf = 0; mf < 4; mf++) s_acc[qs][mf] = (f4v){0.f, 0.f, 0.f, 0.f};
        __builtin_amdgcn_s_setprio(1);
        #pragma unroll
        for (int kc = 0; kc < 2; kc++) {
            const int ko = kc * 32 + quad * 8;
            #pragma unroll
            for (int mf = 0; mf < 4; mf++) {
                s8v kf = *(const s8v*)&Kc[(mf * 16 + l15) * 72 + ko];
                #pragma unroll
                for (int qs = 0; qs < 4; qs++)
                    s_acc[qs][mf] = __builtin_amdgcn_mfma_f32_16x16x32_bf16(
                        kf, qf[qs][kc], s_acc[qs][mf], 0, 0, 0);
            }
        }
        __builtin_amdgcn_s_setprio(0);

        // hardware exp2 + pack; P stored through SHORT-vector type (TBAA-aliases
        // the s8v fragment reads).
        #pragma unroll
        for (int qs = 0; qs < 4; qs++) {
            #pragma unroll
            for (int mf = 0; mf < 4; mf++) {
                float p0 = __builtin_amdgcn_exp2f(s_acc[qs][mf][0]);
                float p1 = __builtin_amdgcn_exp2f(s_acc[qs][mf][1]);
                float p2 = __builtin_amdgcn_exp2f(s_acc[qs][mf][2]);
                float p3 = __builtin_amdgcn_exp2f(s_acc[qs][mf][3]);
                uint2 pk;
                pk.x = cvt_pk_bf16(p0, p1);
                pk.y = cvt_pk_bf16(p2, p3);
                *(s4v*)&Pw[(qs * 16 + l15) * 72 + mf * 16 + quad * 4] =
                    __builtin_bit_cast(s4v, pk);
            }
        }

        // FENCE: no PV-phase ds_read of P may move above the P ds_writes.
        asm volatile("" ::: "memory");
        __builtin_amdgcn_sched_barrier(0);

        // O += P*V; l += P*1 (row-sum on the MFMA pipe). Same-wave LDS ordered.
        #pragma unroll
        for (int kc2 = 0; kc2 < 2; kc2++) {
            const int ko = kc2 * 32 + quad * 8;
            s8v pf[4];
            #pragma unroll
            for (int qs = 0; qs < 4; qs++)
                pf[qs] = *(const s8v*)&Pw[(qs * 16 + l15) * 72 + ko];
            __builtin_amdgcn_s_setprio(1);
            #pragma unroll
            for (int qs = 0; qs < 4; qs++)
                o_l[qs] = __builtin_amdgcn_mfma_f32_16x16x32_bf16(pf[qs], ones, o_l[qs], 0, 0, 0);
            #pragma unroll
            for (int df = 0; df < 4; df++) {
                s8v vf = *(const s8v*)&Vc[(df * 16 + l15) * 72 + ko];
                #pragma unroll
                for (int qs = 0; qs < 4; qs++)
                    o_acc[qs][df] = __builtin_amdgcn_mfma_f32_16x16x32_bf16(
                        pf[qs], vf, o_acc[qs][df], 0, 0, 0);
            }
            __builtin_amdgcn_s_setprio(0);
        }

        // write next tile into the OTHER buffer (last read at tile kt-1; those reads
        // completed before the previous barrier), then ONE barrier.
        if (kt < 31) {
            #pragma unroll
            for (int i = 0; i < 2; i++) {
                int row = srow + i * 32;
                *(s8v*)&Kn[row * 72 + scol] = kreg[i];
                *(s8v*)&Vn[row * 72 + scol] = vreg[i];
            }
        }
        __syncthreads();
    }

    // o_l[qs][r] is the full row-sum for q = qs*16 + quad*4 + r -- exactly o_acc's
    // row layout, so the divide needs no cross-lane movement.
    const int b = bh >> 4, h = bh & (NH - 1);
    #pragma unroll
    for (int qs = 0; qs < 4; qs++) {
        #pragma unroll
        for (int r = 0; r < 4; r++) {
            float lq = 1.0f / o_l[qs][r];
            int s = q0 + w * 64 + qs * 16 + quad * 4 + r;
            #pragma unroll
            for (int df = 0; df < 4; df++)
                AO[((size_t)(b * SEQ + s)) * DIM + h * 64 + df * 16 + l15] =
                    f2bf(o_acc[qs][df][r] * lq);
        }
    }
}

extern "C" void kernel_launch(void* const* d_in, const int* in_sizes, int n_in,
                              void* d_out, int out_size, void* d_ws, size_t ws_size,
                              hipStream_t stream) {
    const float* q  = (const float*)d_in[0];
    const float* k  = (const float*)d_in[1];
    const float* v  = (const float*)d_in[2];
    const float* Wq = (const float*)d_in[3];
    const float* bq = (const float*)d_in[4];
    const float* Wk = (const float*)d_in[5];
    const float* bk = (const float*)d_in[6];
    const float* Wv = (const float*)d_in[7];
    const float* bv = (const float*)d_in[8];
    const float* Wo = (const float*)d_in[9];
    const float* bo = (const float*)d_in[10];
    float* out = (float*)d_out;

    const size_t MK = (size_t)4 * SEQ * DIM;   // 8M elements
    const size_t WK = (size_t)DIM * DIM;
    unsigned short* wsu = (unsigned short*)d_ws;
    unsigned short* qb  = wsu;
    unsigned short* kb  = qb + MK;
    unsigned short* vb  = kb + MK;
    unsigned short* WqT = vb + MK;
    unsigned short* WkT = WqT + WK;
    unsigned short* WvT = WkT + WK;
    unsigned short* WoT = WvT + WK;
    unsigned short* qp  = WoT + WK;            // bf16 [64][2048][64], pre-scaled log2e/8
    unsigned short* kp  = qp + MK;
    unsigned short* vpT = kp + MK;             // bf16 [64][64][2048] (transposed V, fused)
    unsigned short* ao  = vpT + MK;

    const int n4 = (int)(MK / 4);
    conv_all<<<dim3((n4 + 255) / 256, 4), 256, 0, stream>>>(
        q, k, v, qb, kb, vb, n4, Wq, Wk, Wv, Wo, WqT, WkT, WvT, WoT);

    qkv_gemm<<<dim3(DIM / 128, (4 * SEQ) / 128, 3), 256, 0, stream>>>(
        qb, kb, vb, WqT, WkT, WvT, bq, bk, bv, qp, kp, vpT);

    attn_mfma<<<dim3(SEQ / 256, 4 * NH), 256, 0, stream>>>(qp, kp, vpT, ao);

    out_gemm<<<dim3(DIM / 128, (4 * SEQ) / 128), 256, 0, stream>>>(ao, WoT, bo, out);
}

// Round 12
// 342.071 us; speedup vs baseline: 1.0773x; 1.0027x over previous
//
#include <hip/hip_runtime.h>
#include <math.h>

#define SEQ 2048
#define DIM 1024
#define NH 16

typedef short s8v __attribute__((ext_vector_type(8)));
typedef short s4v __attribute__((ext_vector_type(4)));
typedef float f4v __attribute__((ext_vector_type(4)));

__device__ __forceinline__ unsigned short f2bf(float x) {   // RNE
    unsigned u = __float_as_uint(x);
    u += 0x7FFFu + ((u >> 16) & 1u);
    return (unsigned short)(u >> 16);
}
__device__ __forceinline__ unsigned cvt_pk_bf16(float lo, float hi) {
    unsigned r;
    asm("v_cvt_pk_bf16_f32 %0, %1, %2" : "=v"(r) : "v"(lo), "v"(hi));
    return r;
}

// ---------------- fused: q,k,v fp32->bf16  AND  4x W transpose->bf16 ----------------
__global__ __launch_bounds__(256)
void conv_all(const float* __restrict__ q, const float* __restrict__ k,
              const float* __restrict__ v,
              unsigned short* __restrict__ qb, unsigned short* __restrict__ kb,
              unsigned short* __restrict__ vb, int n4,
              const float* __restrict__ W0, const float* __restrict__ W1,
              const float* __restrict__ W2, const float* __restrict__ W3,
              unsigned short* __restrict__ T0, unsigned short* __restrict__ T1,
              unsigned short* __restrict__ T2, unsigned short* __restrict__ T3)
{
    __shared__ float T[64][65];
    const int t = threadIdx.x;
    if (blockIdx.y < 3) {
        const float* in = (blockIdx.y == 0) ? q : (blockIdx.y == 1) ? k : v;
        unsigned short* out = (blockIdx.y == 0) ? qb : (blockIdx.y == 1) ? kb : vb;
        int i = blockIdx.x * 256 + t;
        if (i >= n4) return;
        float4 x = ((const float4*)in)[i];
        ushort4 o;
        o.x = f2bf(x.x); o.y = f2bf(x.y); o.z = f2bf(x.z); o.w = f2bf(x.w);
        ((ushort4*)out)[i] = o;
        return;
    }
    int id = blockIdx.x;
    if (id >= 1024) return;
    const int wz = id >> 8, rem = id & 255;
    const int bxx = rem & 15, byy = rem >> 4;
    const float* W = (wz == 0) ? W0 : (wz == 1) ? W1 : (wz == 2) ? W2 : W3;
    unsigned short* WT = (wz == 0) ? T0 : (wz == 1) ? T1 : (wz == 2) ? T2 : T3;
    const int n0 = bxx * 64, k0 = byy * 64;
    #pragma unroll
    for (int i = 0; i < 4; i++) {
        int idx = t + i * 256;
        int r = idx >> 4, c4 = idx & 15;
        float4 vv = *(const float4*)&W[(size_t)(k0 + r) * DIM + n0 + c4 * 4];
        T[r][c4 * 4 + 0] = vv.x; T[r][c4 * 4 + 1] = vv.y;
        T[r][c4 * 4 + 2] = vv.z; T[r][c4 * 4 + 3] = vv.w;
    }
    __syncthreads();
    #pragma unroll
    for (int i = 0; i < 4; i++) {
        int idx = t + i * 256;
        int rn = idx >> 4, c4 = idx & 15;
        ushort4 o;
        o.x = f2bf(T[c4 * 4 + 0][rn]);
        o.y = f2bf(T[c4 * 4 + 1][rn]);
        o.z = f2bf(T[c4 * 4 + 2][rn]);
        o.w = f2bf(T[c4 * 4 + 3][rn]);
        *(ushort4*)&WT[(size_t)(n0 + rn) * DIM + k0 + c4 * 4] = o;
    }
}

// ---------------- GEMM core (m97 staging), shared by qkv+out projections ----------
// LDS is passed in by the caller (ONE kernel-scope allocation) -- function-scope
// __shared__ inside a template gets a separate allocation PER INSTANTIATION
// (r11: qkv_gemm carried 2x34.8KB = 69632B, halving occupancy to 2 blocks/CU).
template<int MODE>
__device__ __forceinline__
void gemm_core(unsigned short* __restrict__ smem,
               const unsigned short* __restrict__ A,
               const unsigned short* __restrict__ BT,
               const float* __restrict__ bias, void* __restrict__ outp,
               float scale, int bx, int by)
{
    unsigned short* As = smem;
    unsigned short* Bs = smem + 128 * 64;
    const int t = threadIdx.x;
    const int lane = t & 63, w = t >> 6;
    const int l15 = lane & 15, quad = lane >> 4;
    const int bm = by * 128, bn = bx * 128;
    const int wm = (w & 1) * 64, wn = (w >> 1) * 64;
    const int lrow = lane >> 3, lcol = (lane & 7) * 8;

    f4v acc[4][4];
    #pragma unroll
    for (int mi = 0; mi < 4; mi++)
        #pragma unroll
        for (int ni = 0; ni < 4; ni++)
            acc[mi][ni] = (f4v){0.f, 0.f, 0.f, 0.f};

    for (int k0 = 0; k0 < DIM; k0 += 64) {
        __syncthreads();
        #pragma unroll
        for (int i = 0; i < 4; i++) {
            int ci = w + i * 4;
            int row = ci * 8 + lrow;
            __builtin_amdgcn_global_load_lds(
                (const __attribute__((address_space(1))) unsigned int*)
                    (A + (size_t)(bm + row) * DIM + k0 + lcol),
                (__attribute__((address_space(3))) unsigned int*)(As + ci * 8 * 64),
                16, 0, 0);
            __builtin_amdgcn_global_load_lds(
                (const __attribute__((address_space(1))) unsigned int*)
                    (BT + (size_t)(bn + row) * DIM + k0 + lcol),
                (__attribute__((address_space(3))) unsigned int*)(Bs + ci * 8 * 64),
                16, 0, 0);
        }
        __syncthreads();
        #pragma unroll
        for (int kc = 0; kc < 2; kc++) {
            const int ko = kc * 32 + quad * 8;
            s8v af[4], bf[4];
            #pragma unroll
            for (int mi = 0; mi < 4; mi++)
                af[mi] = *(const s8v*)&As[(wm + mi * 16 + l15) * 64 + ko];
            #pragma unroll
            for (int ni = 0; ni < 4; ni++)
                bf[ni] = *(const s8v*)&Bs[(wn + ni * 16 + l15) * 64 + ko];
            #pragma unroll
            for (int mi = 0; mi < 4; mi++)
                #pragma unroll
                for (int ni = 0; ni < 4; ni++)
                    acc[mi][ni] = __builtin_amdgcn_mfma_f32_16x16x32_bf16(
                        af[mi], bf[ni], acc[mi][ni], 0, 0, 0);
        }
    }

    if (MODE == 0) {
        #pragma unroll
        for (int mi = 0; mi < 4; mi++)
            #pragma unroll
            for (int ni = 0; ni < 4; ni++)
                #pragma unroll
                for (int r = 0; r < 4; r++) {
                    int m = bm + wm + mi * 16 + quad * 4 + r;
                    int n = bn + wn + ni * 16 + l15;
                    ((float*)outp)[(size_t)m * DIM + n] = acc[mi][ni][r] + bias[n];
                }
    } else {
        __syncthreads();
        unsigned short* Cs = smem;    // [128][136] padded bf16 C tile
        if (MODE == 1) {
            #pragma unroll
            for (int mi = 0; mi < 4; mi++)
                #pragma unroll
                for (int ni = 0; ni < 4; ni++)
                    #pragma unroll
                    for (int r = 0; r < 4; r++) {
                        int ml = wm + mi * 16 + quad * 4 + r;
                        int nl = wn + ni * 16 + l15;
                        float val = (acc[mi][ni][r] + bias[bn + nl]) * scale;
                        Cs[ml * 136 + nl] = f2bf(val);
                    }
        } else {
            #pragma unroll
            for (int mi = 0; mi < 4; mi++)
                #pragma unroll
                for (int ni = 0; ni < 4; ni++) {
                    int nl = wn + ni * 16 + l15;
                    int m0 = wm + mi * 16 + quad * 4;
                    s4v o;
                    #pragma unroll
                    for (int r = 0; r < 4; r++)
                        o[r] = (short)f2bf(acc[mi][ni][r] + bias[bn + nl]);
                    *(s4v*)&Cs[nl * 136 + m0] = o;
                }
        }
        __syncthreads();
        #pragma unroll
        for (int it = 0; it < 8; it++) {
            int idx = t + it * 256;
            int rr = idx >> 4, cc = (idx & 15) * 8;
            if (MODE == 1) {
                int m = bm + rr, n = bn + cc;
                int b = m >> 11, s = m & (SEQ - 1);
                int h = n >> 6, dk = n & 63;
                *(s8v*)&((unsigned short*)outp)[(((size_t)(b * NH + h)) * SEQ + s) * 64 + dk] =
                    *(const s8v*)&Cs[rr * 136 + cc];
            } else {
                int n = bn + rr, m0 = bm + cc;
                int b = m0 >> 11, s = m0 & (SEQ - 1);
                int h = n >> 6, dk = n & 63;
                *(s8v*)&((unsigned short*)outp)[((size_t)(b * NH + h) * 64 + dk) * SEQ + s] =
                    *(const s8v*)&Cs[rr * 136 + cc];
            }
        }
    }
}

// XCD-aware bijective swizzle for an (NX x NY) grid dispatched x-fastest.
template<int NX, int NWG>
__device__ __forceinline__ void xcd_swizzle(int& bx, int& by) {
    const int lin = by * NX + bx;
    const int lin2 = (lin & 7) * (NWG >> 3) + (lin >> 3);
    bx = lin2 % NX;
    by = lin2 / NX;
}

__global__ __launch_bounds__(256)
void qkv_gemm(const unsigned short* __restrict__ qb, const unsigned short* __restrict__ kb,
              const unsigned short* __restrict__ vb,
              const unsigned short* __restrict__ WqT, const unsigned short* __restrict__ WkT,
              const unsigned short* __restrict__ WvT,
              const float* __restrict__ bq, const float* __restrict__ bk,
              const float* __restrict__ bv,
              unsigned short* __restrict__ qp, unsigned short* __restrict__ kp,
              unsigned short* __restrict__ vpT)
{
    __shared__ __align__(16) unsigned short smem[17408];   // ONE allocation (34.8 KB)
    int bx = blockIdx.x, by = blockIdx.y;
    xcd_swizzle<8, 512>(bx, by);
    const int z = blockIdx.z;
    if (z == 0) {
        gemm_core<1>(smem, qb, WqT, bq, qp, 0.18033688011112042f, bx, by);
    } else if (z == 1) {
        gemm_core<1>(smem, kb, WkT, bk, kp, 1.0f, bx, by);
    } else {
        gemm_core<2>(smem, vb, WvT, bv, vpT, 1.0f, bx, by);
    }
}

__global__ __launch_bounds__(256)
void out_gemm(const unsigned short* __restrict__ A, const unsigned short* __restrict__ BT,
              const float* __restrict__ bias, float* __restrict__ outp)
{
    __shared__ __align__(16) unsigned short smem[17408];
    int bx = blockIdx.x, by = blockIdx.y;
    xcd_swizzle<8, 512>(bx, by);
    gemm_core<0>(smem, A, BT, bias, outp, 1.0f, bx, by);
}

// ---------------- MFMA flash attention v13: 64 q-rows per wave (r11, unchanged) ----
__global__ __launch_bounds__(256, 2)
void attn_mfma(const unsigned short* __restrict__ Q,
               const unsigned short* __restrict__ Kp,
               const unsigned short* __restrict__ VT,
               unsigned short* __restrict__ AO)
{
    __shared__ __align__(16) unsigned short Ks[2][64 * 72];  // [buf][key][d]
    __shared__ __align__(16) unsigned short Vs[2][64 * 72];  // [buf][d][key]
    __shared__ __align__(16) unsigned short Ps[4][64 * 72];  // per-wave P [q=64][key]
    const int t = threadIdx.x;
    const int lane = t & 63, w = t >> 6;
    const int l15 = lane & 15, quad = lane >> 4;

    int bxs = blockIdx.x, bys = blockIdx.y;
    xcd_swizzle<8, 512>(bxs, bys);   // cluster same-head blocks per XCD L2
    const int bh = bys, q0 = bxs * 256;

    const unsigned short* qbase = Q + ((size_t)bh * SEQ + q0 + w * 64) * 64;
    const unsigned short* kbase = Kp + (size_t)bh * SEQ * 64;
    const unsigned short* vtbase = VT + (size_t)bh * 64 * SEQ;

    // Q B-frags: B[n=l15 -> q=qs*16+l15][k=kc*32+quad*8+j -> d], qs = 0..3
    s8v qf[4][2];
    #pragma unroll
    for (int qs = 0; qs < 4; qs++)
        #pragma unroll
        for (int kc = 0; kc < 2; kc++)
            qf[qs][kc] = *(const s8v*)&qbase[(qs * 16 + l15) * 64 + kc * 32 + quad * 8];

    f4v o_acc[4][4];   // [qs][df]
    #pragma unroll
    for (int qs = 0; qs < 4; qs++)
        #pragma unroll
        for (int df = 0; df < 4; df++) o_acc[qs][df] = (f4v){0.f, 0.f, 0.f, 0.f};
    f4v o_l[4];        // row-sum accumulators (l = P*ones), same D-layout as o_acc
    #pragma unroll
    for (int qs = 0; qs < 4; qs++) o_l[qs] = (f4v){0.f, 0.f, 0.f, 0.f};
    const s8v ones = {0x3F80, 0x3F80, 0x3F80, 0x3F80, 0x3F80, 0x3F80, 0x3F80, 0x3F80};

    const int srow = t >> 3, scol = (t & 7) * 8;
    unsigned short* Pw = (unsigned short*)Ps[w];

    // prologue: stage tile 0 into buf 0 (reg round-trip)
    s8v kreg[2], vreg[2];
    #pragma unroll
    for (int i = 0; i < 2; i++) {
        int row = srow + i * 32;
        kreg[i] = *(const s8v*)&kbase[(size_t)row * 64 + scol];
        vreg[i] = *(const s8v*)&vtbase[(size_t)row * SEQ + scol];
    }
    #pragma unroll
    for (int i = 0; i < 2; i++) {
        int row = srow + i * 32;
        *(s8v*)&Ks[0][row * 72 + scol] = kreg[i];
        *(s8v*)&Vs[0][row * 72 + scol] = vreg[i];
    }
    __syncthreads();

    for (int kt = 0; kt < 32; kt++) {
        const unsigned short* Kc = Ks[kt & 1];
        const unsigned short* Vc = Vs[kt & 1];
        unsigned short* Kn = Ks[(kt + 1) & 1];
        unsigned short* Vn = Vs[(kt + 1) & 1];

        // issue next-tile loads NOW; consumed by the ds_write just before the barrier.
        if (kt < 31) {
            #pragma unroll
            for (int i = 0; i < 2; i++) {
                int row = srow + i * 32;
                kreg[i] = *(const s8v*)&kbase[((size_t)((kt + 1) * 64 + row)) * 64 + scol];
                vreg[i] = *(const s8v*)&vtbase[(size_t)row * SEQ + (kt + 1) * 64 + scol];
            }
        }

        // S^T = K*Q^T: A=kf (m=key), B=qf (n=q). Each kf read serves FOUR q-slices.
        f4v s_acc[4][4];   // [qs][mf]: S^T[key=mf*16+quad*4+r][q=qs*16+l15]
        #pragma unroll
        for (int qs = 0; qs < 4; qs++)
            #pragma unroll
            for (int mf = 0; mf < 4; mf++) s_acc[qs][mf] = (f4v){0.f, 0.f, 0.f, 0.f};
        __builtin_amdgcn_s_setprio(1);
        #pragma unroll
        for (int kc = 0; kc < 2; kc++) {
            const int ko = kc * 32 + quad * 8;
            #pragma unroll
            for (int mf = 0; mf < 4; mf++) {
                s8v kf = *(const s8v*)&Kc[(mf * 16 + l15) * 72 + ko];
                #pragma unroll
                for (int qs = 0; qs < 4; qs++)
                    s_acc[qs][mf] = __builtin_amdgcn_mfma_f32_16x16x32_bf16(
                        kf, qf[qs][kc], s_acc[qs][mf], 0, 0, 0);
            }
        }
        __builtin_amdgcn_s_setprio(0);

        // hardware exp2 + pack; P stored through SHORT-vector type (TBAA-aliases
        // the s8v fragment reads).
        #pragma unroll
        for (int qs = 0; qs < 4; qs++) {
            #pragma unroll
            for (int mf = 0; mf < 4; mf++) {
                float p0 = __builtin_amdgcn_exp2f(s_acc[qs][mf][0]);
                float p1 = __builtin_amdgcn_exp2f(s_acc[qs][mf][1]);
                float p2 = __builtin_amdgcn_exp2f(s_acc[qs][mf][2]);
                float p3 = __builtin_amdgcn_exp2f(s_acc[qs][mf][3]);
                uint2 pk;
                pk.x = cvt_pk_bf16(p0, p1);
                pk.y = cvt_pk_bf16(p2, p3);
                *(s4v*)&Pw[(qs * 16 + l15) * 72 + mf * 16 + quad * 4] =
                    __builtin_bit_cast(s4v, pk);
            }
        }

        // FENCE: no PV-phase ds_read of P may move above the P ds_writes.
        asm volatile("" ::: "memory");
        __builtin_amdgcn_sched_barrier(0);

        // O += P*V; l += P*1 (row-sum on the MFMA pipe). Same-wave LDS ordered.
        #pragma unroll
        for (int kc2 = 0; kc2 < 2; kc2++) {
            const int ko = kc2 * 32 + quad * 8;
            s8v pf[4];
            #pragma unroll
            for (int qs = 0; qs < 4; qs++)
                pf[qs] = *(const s8v*)&Pw[(qs * 16 + l15) * 72 + ko];
            __builtin_amdgcn_s_setprio(1);
            #pragma unroll
            for (int qs = 0; qs < 4; qs++)
                o_l[qs] = __builtin_amdgcn_mfma_f32_16x16x32_bf16(pf[qs], ones, o_l[qs], 0, 0, 0);
            #pragma unroll
            for (int df = 0; df < 4; df++) {
                s8v vf = *(const s8v*)&Vc[(df * 16 + l15) * 72 + ko];
                #pragma unroll
                for (int qs = 0; qs < 4; qs++)
                    o_acc[qs][df] = __builtin_amdgcn_mfma_f32_16x16x32_bf16(
                        pf[qs], vf, o_acc[qs][df], 0, 0, 0);
            }
            __builtin_amdgcn_s_setprio(0);
        }

        // write next tile into the OTHER buffer (last read at tile kt-1; those reads
        // completed before the previous barrier), then ONE barrier.
        if (kt < 31) {
            #pragma unroll
            for (int i = 0; i < 2; i++) {
                int row = srow + i * 32;
                *(s8v*)&Kn[row * 72 + scol] = kreg[i];
                *(s8v*)&Vn[row * 72 + scol] = vreg[i];
            }
        }
        __syncthreads();
    }

    // o_l[qs][r] is the full row-sum for q = qs*16 + quad*4 + r -- exactly o_acc's
    // row layout, so the divide needs no cross-lane movement.
    const int b = bh >> 4, h = bh & (NH - 1);
    #pragma unroll
    for (int qs = 0; qs < 4; qs++) {
        #pragma unroll
        for (int r = 0; r < 4; r++) {
            float lq = 1.0f / o_l[qs][r];
            int s = q0 + w * 64 + qs * 16 + quad * 4 + r;
            #pragma unroll
            for (int df = 0; df < 4; df++)
                AO[((size_t)(b * SEQ + s)) * DIM + h * 64 + df * 16 + l15] =
                    f2bf(o_acc[qs][df][r] * lq);
        }
    }
}

extern "C" void kernel_launch(void* const* d_in, const int* in_sizes, int n_in,
                              void* d_out, int out_size, void* d_ws, size_t ws_size,
                              hipStream_t stream) {
    const float* q  = (const float*)d_in[0];
    const float* k  = (const float*)d_in[1];
    const float* v  = (const float*)d_in[2];
    const float* Wq = (const float*)d_in[3];
    const float* bq = (const float*)d_in[4];
    const float* Wk = (const float*)d_in[5];
    const float* bk = (const float*)d_in[6];
    const float* Wv = (const float*)d_in[7];
    const float* bv = (const float*)d_in[8];
    const float* Wo = (const float*)d_in[9];
    const float* bo = (const float*)d_in[10];
    float* out = (float*)d_out;

    const size_t MK = (size_t)4 * SEQ * DIM;   // 8M elements
    const size_t WK = (size_t)DIM * DIM;
    unsigned short* wsu = (unsigned short*)d_ws;
    unsigned short* qb  = wsu;
    unsigned short* kb  = qb + MK;
    unsigned short* vb  = kb + MK;
    unsigned short* WqT = vb + MK;
    unsigned short* WkT = WqT + WK;
    unsigned short* WvT = WkT + WK;
    unsigned short* WoT = WvT + WK;
    unsigned short* qp  = WoT + WK;            // bf16 [64][2048][64], pre-scaled log2e/8
    unsigned short* kp  = qp + MK;
    unsigned short* vpT = kp + MK;             // bf16 [64][64][2048] (transposed V, fused)
    unsigned short* ao  = vpT + MK;

    const int n4 = (int)(MK / 4);
    conv_all<<<dim3((n4 + 255) / 256, 4), 256, 0, stream>>>(
        q, k, v, qb, kb, vb, n4, Wq, Wk, Wv, Wo, WqT, WkT, WvT, WoT);

    qkv_gemm<<<dim3(DIM / 128, (4 * SEQ) / 128, 3), 256, 0, stream>>>(
        qb, kb, vb, WqT, WkT, WvT, bq, bk, bv, qp, kp, vpT);

    attn_mfma<<<dim3(SEQ / 256, 4 * NH), 256, 0, stream>>>(qp, kp, vpT, ao);

    out_gemm<<<dim3(DIM / 128, (4 * SEQ) / 128), 256, 0, stream>>>(ao, WoT, bo, out);
}